// Round 1
// baseline (1567.406 us; speedup 1.0000x reference)
//
#include <hip/hip_runtime.h>
#include <math.h>

#define A_N 64
#define B_N 4096
#define D_N 50
#define H_N 192
#define O_N 3

__device__ __forceinline__ float gelu_exact(float t) {
    // exact GELU: 0.5*t*(1+erf(t/sqrt(2)))  (matches jax approximate=False)
    return 0.5f * t * (1.0f + erff(t * 0.70710678118654752440f));
}

// 24-column dual-matrix GEMM slice. act in LDS laid out [k][row] (row=lane).
// Weight addresses are wave-uniform (h0 from readfirstlane) -> s_load + v_fmac v,s,v.
template<int K, bool DUAL>
__device__ __forceinline__ void gemm24(const float* __restrict__ W,
                                       const float* __restrict__ S,
                                       const float* act_lds, int lane, int h0,
                                       float* __restrict__ accT,
                                       float* __restrict__ accS) {
    constexpr int KT = (K / 16) * 16;
    #pragma unroll 1
    for (int kt = 0; kt < KT; kt += 16) {
        float act[16];
        #pragma unroll
        for (int i = 0; i < 16; ++i) act[i] = act_lds[(kt + i) * 64 + lane];
        #pragma unroll
        for (int j = 0; j < 24; ++j) {
            const float* wp = W + (h0 + j) * K + kt;
            #pragma unroll
            for (int i = 0; i < 16; ++i) accT[j] = fmaf(act[i], wp[i], accT[j]);
            if constexpr (DUAL) {
                const float* sp = S + (h0 + j) * K + kt;
                #pragma unroll
                for (int i = 0; i < 16; ++i) accS[j] = fmaf(act[i], sp[i], accS[j]);
            }
        }
    }
    if constexpr (K > KT) {
        constexpr int R = K - KT;
        float act[R];
        #pragma unroll
        for (int i = 0; i < R; ++i) act[i] = act_lds[(KT + i) * 64 + lane];
        #pragma unroll
        for (int j = 0; j < 24; ++j) {
            const float* wp = W + (h0 + j) * K + KT;
            #pragma unroll
            for (int i = 0; i < R; ++i) accT[j] = fmaf(act[i], wp[i], accT[j]);
            if constexpr (DUAL) {
                const float* sp = S + (h0 + j) * K + KT;
                #pragma unroll
                for (int i = 0; i < R; ++i) accS[j] = fmaf(act[i], sp[i], accS[j]);
            }
        }
    }
}

__global__ __launch_bounds__(512, 4)
void srek_kernel(const float* __restrict__ x,
                 const float* __restrict__ inw, const float* __restrict__ inb,
                 const float* __restrict__ w1,  const float* __restrict__ b1,
                 const float* __restrict__ w2,  const float* __restrict__ b2,
                 const float* __restrict__ w3,  const float* __restrict__ b3,
                 const float* __restrict__ ow,  const float* __restrict__ ob,
                 const float* __restrict__ s1w, const float* __restrict__ s1b,
                 const float* __restrict__ s2w, const float* __restrict__ s2b,
                 const float* __restrict__ hnw, const float* __restrict__ hnb,
                 float* __restrict__ out) {
    // LDS: activations stored [k][row] (stride 64 -> lane-consecutive, conflict-free)
    __shared__ float lds_xn[D_N * 64];   // 12.8 KB, reused for output weights later
    __shared__ float lds_h [H_N * 64];   // 49.2 KB, h1 -> h2 -> h3 (barrier-reused)

    const int bid  = blockIdx.x;
    // XCD-aware swizzle: bid%8 = XCD; keep one agent's 0.52 MB weights hot per XCD L2.
    const int slot = bid >> 3;
    const int tile = slot & 63;
    const int a    = ((bid & 7) << 3) | (slot >> 6);

    const int tid  = threadIdx.x;
    const int lane = tid & 63;                                  // lane == batch row in tile
    const int w    = __builtin_amdgcn_readfirstlane(tid >> 6);  // wave id, force scalar
    const int h0   = w * 24;                                    // this wave's H-column slice
    const int row0 = tile * 64;

    const size_t aHD = (size_t)a * H_N * D_N;
    const size_t aHH = (size_t)a * H_N * H_N;
    const int    aH  = a * H_N;

    // ---- stage x_norm = x*inw + inb into LDS [d][row] ----
    for (int e = tid; e < D_N * 64; e += 512) {
        int d = e >> 6, r = e & 63;
        lds_xn[e] = x[(size_t)(row0 + r) * D_N + d] * inw[a * D_N + d] + inb[a * D_N + d];
    }
    __syncthreads();

    float accT[24], accS[24];

    // ---- layer1 + skip1 (K=50) ----
    #pragma unroll
    for (int j = 0; j < 24; ++j) { accT[j] = 0.f; accS[j] = 0.f; }
    gemm24<D_N, true>(w1 + aHD, s1w + aHD, lds_xn, lane, h0, accT, accS);
    #pragma unroll
    for (int j = 0; j < 24; ++j) {
        int h = h0 + j;
        float g = gelu_exact(accT[j] + b1[aH + h]);
        lds_h[h * 64 + lane] = g + accS[j] + s1b[aH + h];   // h1, fresh region: no barrier needed
    }
    __syncthreads();

    // ---- layer2 + skip2 (K=192) ----
    #pragma unroll
    for (int j = 0; j < 24; ++j) { accT[j] = 0.f; accS[j] = 0.f; }
    gemm24<H_N, true>(w2 + aHH, s2w + aHH, lds_h, lane, h0, accT, accS);
    float h2v[24];
    #pragma unroll
    for (int j = 0; j < 24; ++j) {
        int h = h0 + j;
        h2v[j] = gelu_exact(accT[j] + b2[aH + h]) + accS[j] + s2b[aH + h];
    }
    __syncthreads();   // all waves done reading h1
    #pragma unroll
    for (int j = 0; j < 24; ++j) lds_h[(h0 + j) * 64 + lane] = h2v[j];
    __syncthreads();

    // ---- layer3 + residual + hidden_norm (K=192) ----
    #pragma unroll
    for (int j = 0; j < 24; ++j) accT[j] = 0.f;
    gemm24<H_N, false>(w3 + aHH, nullptr, lds_h, lane, h0, accT, accS);
    float h3v[24];
    #pragma unroll
    for (int j = 0; j < 24; ++j) {
        int h = h0 + j;
        float v = accT[j] + b3[aH + h] + lds_h[h * 64 + lane];  // + h2 residual (pre-overwrite)
        h3v[j] = v * hnw[aH + h] + hnb[aH + h];
    }
    __syncthreads();   // all waves done reading h2
    #pragma unroll
    for (int j = 0; j < 24; ++j) lds_h[(h0 + j) * 64 + lane] = h3v[j];

    // stage output weights into freed xn region, stride 193 to dodge bank aliasing
    for (int e = tid; e < O_N * H_N; e += 512) {
        int o = e / H_N, k = e - o * H_N;
        lds_xn[o * 193 + k] = ow[(size_t)a * O_N * H_N + e];
    }
    __syncthreads();

    // ---- output GEMM (O=3, K=192): thread (row=tid>>3, o=tid&7), o<3 active ----
    {
        int r = tid >> 3, o = tid & 7;
        if (o < O_N) {
            float acc = 0.f;
            #pragma unroll 8
            for (int k = 0; k < H_N; ++k)
                acc = fmaf(lds_h[k * 64 + r], lds_xn[o * 193 + k], acc);
            out[((size_t)a * B_N + row0 + r) * O_N + o] = acc + ob[a * O_N + o];
        }
    }
}

extern "C" void kernel_launch(void* const* d_in, const int* in_sizes, int n_in,
                              void* d_out, int out_size, void* d_ws, size_t ws_size,
                              hipStream_t stream) {
    const float* x   = (const float*)d_in[0];
    const float* inw = (const float*)d_in[1];
    const float* inb = (const float*)d_in[2];
    const float* w1  = (const float*)d_in[3];
    const float* b1  = (const float*)d_in[4];
    const float* w2  = (const float*)d_in[5];
    const float* b2  = (const float*)d_in[6];
    const float* w3  = (const float*)d_in[7];
    const float* b3  = (const float*)d_in[8];
    const float* ow  = (const float*)d_in[9];
    const float* ob  = (const float*)d_in[10];
    const float* s1w = (const float*)d_in[11];
    const float* s1b = (const float*)d_in[12];
    const float* s2w = (const float*)d_in[13];
    const float* s2b = (const float*)d_in[14];
    const float* hnw = (const float*)d_in[15];
    const float* hnb = (const float*)d_in[16];

    srek_kernel<<<dim3(A_N * (B_N / 64)), dim3(512), 0, stream>>>(
        x, inw, inb, w1, b1, w2, b2, w3, b3, ow, ob,
        s1w, s1b, s2w, s2b, hnw, hnb, (float*)d_out);
}

// Round 2
// 322.932 us; speedup vs baseline: 4.8537x; 4.8537x over previous
//
#include <hip/hip_runtime.h>
#include <math.h>

#define A_N 64
#define B_N 4096
#define D_N 50
#define H_N 192
#define O_N 3

typedef __attribute__((ext_vector_type(8))) __bf16 bf16x8;
typedef __attribute__((ext_vector_type(4))) float f32x4;

// ws layout (bf16 elems), all frag-packed: [a][nt][ks][lane][8]
// frag elem (lane,j) = W[nt*16 + (lane&15)][ks*32 + (lane>>4)*8 + j]
#define W1_OFF   0          // [A][12][2][512]  K=64 (padded from 50)
#define S1_OFF   786432
#define W2_OFF   1572864    // [A][12][6][512]  K=192
#define S2_OFF   3932160
#define W3_OFF   6291456
#define OW_OFF   8650752    // [A][1][6][512]   N=16 (padded from 3), K=192
#define WS_ELEMS 8847360    // *2 bytes = 17.7 MB of d_ws

__device__ __forceinline__ float gelu_exact(float t) {
    return 0.5f * t * (1.0f + erff(t * 0.70710678118654752440f));
}

__global__ void prep_kernel(const float* __restrict__ w1, const float* __restrict__ s1,
                            const float* __restrict__ w2, const float* __restrict__ s2,
                            const float* __restrict__ w3, const float* __restrict__ ow,
                            __bf16* __restrict__ ws) {
    int idx = blockIdx.x * 256 + threadIdx.x;
    if (idx >= WS_ELEMS) return;
    if (idx < W2_OFF) {
        // w1/s1: [192][50] -> frag-packed K=64 padded
        const float* src = (idx < S1_OFF) ? w1 : s1;
        int r = (idx < S1_OFF) ? idx : idx - S1_OFF;
        int a = r / 12288;  r %= 12288;
        int nt = r / 1024;  r %= 1024;     // KS=2 -> nt block = 2*512
        int ks = r / 512;   r %= 512;
        int lane = r >> 3, j = r & 7;
        int n = nt * 16 + (lane & 15);
        int k = ks * 32 + (lane >> 4) * 8 + j;
        ws[idx] = (k < D_N) ? (__bf16)src[(a * H_N + n) * D_N + k] : (__bf16)0.f;
    } else if (idx < OW_OFF) {
        int r = idx - W2_OFF;
        const float* src = w2;
        if (r >= 4718592)      { src = w3; r -= 4718592; }
        else if (r >= 2359296) { src = s2; r -= 2359296; }
        int a = r / 36864;  r %= 36864;
        int nt = r / 3072;  r %= 3072;     // KS=6 -> nt block = 6*512
        int ks = r / 512;   r %= 512;
        int lane = r >> 3, j = r & 7;
        int n = nt * 16 + (lane & 15);
        int k = ks * 32 + (lane >> 4) * 8 + j;
        ws[idx] = (__bf16)src[(a * H_N + n) * H_N + k];
    } else {
        int r = idx - OW_OFF;
        int a = r / 3072;   r %= 3072;
        int ks = r / 512;   r %= 512;
        int lane = r >> 3, j = r & 7;
        int n = lane & 15;
        int k = ks * 32 + (lane >> 4) * 8 + j;
        ws[idx] = (n < O_N) ? (__bf16)ow[(a * O_N + n) * H_N + k] : (__bf16)0.f;
    }
}

#define MFMA(a, b, c) __builtin_amdgcn_mfma_f32_16x16x32_bf16((a), (b), (c), 0, 0, 0)

__global__ __launch_bounds__(512, 4)
void srek_mfma(const float* __restrict__ x,
               const float* __restrict__ inw, const float* __restrict__ inb,
               const float* __restrict__ b1,  const float* __restrict__ b2,
               const float* __restrict__ b3,  const float* __restrict__ s1b,
               const float* __restrict__ s2b, const float* __restrict__ hnw,
               const float* __restrict__ hnb, const float* __restrict__ ob,
               const __bf16* __restrict__ ws, float* __restrict__ out) {
    // Activations, [row][k] bf16, hi + lo split (A = Ahi+Alo exact to 2^-18).
    // Pitches: dword-stride mod 32 == 4 -> 16-lane b128 starts hit 8 banks x2 (free).
    __shared__ __bf16 Xhi[64 * 72],  Xlo[64 * 72];    // x_norm, K=64 padded
    __shared__ __bf16 Hhi[64 * 200], Hlo[64 * 200];   // h1 -> h2 -> h3 (barrier-reused)

    const int bid  = blockIdx.x;
    const int slot = bid >> 3;
    const int tile = slot & 63;
    const int a    = ((bid & 7) << 3) | (slot >> 6);   // XCD-aware: agent pinned to XCD
    const int row0 = tile * 64;

    const int tid   = threadIdx.x;
    const int lane  = tid & 63;
    const int wv    = tid >> 6;
    const int mtile = wv & 3;        // 16-row stripe
    const int nhalf = wv >> 2;       // 96-col half
    const int ln    = lane & 15;
    const int quad  = lane >> 4;
    const int aH    = a * H_N;

    // ---- stage x_norm = x*inw + inb (fp32) -> Xhi/Xlo ----
    for (int e = tid; e < 64 * 64; e += 512) {
        int r = e >> 6, k = e & 63;
        float v = 0.f;
        if (k < D_N) v = x[(size_t)(row0 + r) * D_N + k] * inw[a * D_N + k] + inb[a * D_N + k];
        __bf16 h = (__bf16)v;
        Xhi[r * 72 + k] = h;
        Xlo[r * 72 + k] = (__bf16)(v - (float)h);
    }
    __syncthreads();

    const f32x4 zero = {0.f, 0.f, 0.f, 0.f};
    f32x4 accT[6], accS[6];

    // ---- layer1 + skip1 (K=64) ----
    #pragma unroll
    for (int i = 0; i < 6; ++i) { accT[i] = zero; accS[i] = zero; }
    {
        const __bf16* W = ws + W1_OFF + a * 12288;
        const __bf16* S = ws + S1_OFF + a * 12288;
        #pragma unroll
        for (int ks = 0; ks < 2; ++ks) {
            int av = (mtile * 16 + ln) * 72 + ks * 32 + quad * 8;
            bf16x8 ah = *(const bf16x8*)&Xhi[av];
            bf16x8 al = *(const bf16x8*)&Xlo[av];
            #pragma unroll
            for (int nt = 0; nt < 6; ++nt) {
                int fo = ((nhalf * 6 + nt) * 2 + ks) * 512 + lane * 8;
                bf16x8 bw = *(const bf16x8*)&W[fo];
                bf16x8 bs = *(const bf16x8*)&S[fo];
                accT[nt] = MFMA(ah, bw, accT[nt]);
                accT[nt] = MFMA(al, bw, accT[nt]);
                accS[nt] = MFMA(ah, bs, accS[nt]);
                accS[nt] = MFMA(al, bs, accS[nt]);
            }
        }
    }
    // h1 = gelu(T + b1) + S + s1b  -> Hhi/Hlo (fresh region, disjoint per wave)
    #pragma unroll
    for (int nt = 0; nt < 6; ++nt) {
        int col = nhalf * 96 + nt * 16 + ln;
        float bb = b1[aH + col], sb = s1b[aH + col];
        #pragma unroll
        for (int rg = 0; rg < 4; ++rg) {
            float v = gelu_exact(accT[nt][rg] + bb) + accS[nt][rg] + sb;
            int ad = (mtile * 16 + quad * 4 + rg) * 200 + col;
            __bf16 h = (__bf16)v;
            Hhi[ad] = h;
            Hlo[ad] = (__bf16)(v - (float)h);
        }
    }
    __syncthreads();

    // ---- layer2 + skip2 (K=192) ----
    #pragma unroll
    for (int i = 0; i < 6; ++i) { accT[i] = zero; accS[i] = zero; }
    {
        const __bf16* W = ws + W2_OFF + a * 36864;
        const __bf16* S = ws + S2_OFF + a * 36864;
        #pragma unroll 1
        for (int ks = 0; ks < 6; ++ks) {
            int av = (mtile * 16 + ln) * 200 + ks * 32 + quad * 8;
            bf16x8 ah = *(const bf16x8*)&Hhi[av];
            bf16x8 al = *(const bf16x8*)&Hlo[av];
            #pragma unroll
            for (int nt = 0; nt < 6; ++nt) {
                int fo = ((nhalf * 6 + nt) * 6 + ks) * 512 + lane * 8;
                bf16x8 bw = *(const bf16x8*)&W[fo];
                bf16x8 bs = *(const bf16x8*)&S[fo];
                accT[nt] = MFMA(ah, bw, accT[nt]);
                accT[nt] = MFMA(al, bw, accT[nt]);
                accS[nt] = MFMA(ah, bs, accS[nt]);
                accS[nt] = MFMA(al, bs, accS[nt]);
            }
        }
    }
    f32x4 h2f[6];
    #pragma unroll
    for (int nt = 0; nt < 6; ++nt) {
        int col = nhalf * 96 + nt * 16 + ln;
        float bb = b2[aH + col], sb = s2b[aH + col];
        #pragma unroll
        for (int rg = 0; rg < 4; ++rg)
            h2f[nt][rg] = gelu_exact(accT[nt][rg] + bb) + accS[nt][rg] + sb;
    }
    __syncthreads();   // all waves done reading h1
    #pragma unroll
    for (int nt = 0; nt < 6; ++nt) {
        int col = nhalf * 96 + nt * 16 + ln;
        #pragma unroll
        for (int rg = 0; rg < 4; ++rg) {
            int ad = (mtile * 16 + quad * 4 + rg) * 200 + col;
            __bf16 h = (__bf16)h2f[nt][rg];
            Hhi[ad] = h;
            Hlo[ad] = (__bf16)(h2f[nt][rg] - (float)h);
        }
    }
    __syncthreads();

    // ---- layer3 (K=192, single matrix) + residual + hidden_norm ----
    f32x4 acc3[6];
    #pragma unroll
    for (int i = 0; i < 6; ++i) acc3[i] = zero;
    {
        const __bf16* W = ws + W3_OFF + a * 36864;
        #pragma unroll 1
        for (int ks = 0; ks < 6; ++ks) {
            int av = (mtile * 16 + ln) * 200 + ks * 32 + quad * 8;
            bf16x8 ah = *(const bf16x8*)&Hhi[av];
            bf16x8 al = *(const bf16x8*)&Hlo[av];
            #pragma unroll
            for (int nt = 0; nt < 6; ++nt) {
                int fo = ((nhalf * 6 + nt) * 6 + ks) * 512 + lane * 8;
                bf16x8 bw = *(const bf16x8*)&W[fo];
                acc3[nt] = MFMA(ah, bw, acc3[nt]);
                acc3[nt] = MFMA(al, bw, acc3[nt]);
            }
        }
    }
    f32x4 h3f[6];
    #pragma unroll
    for (int nt = 0; nt < 6; ++nt) {
        int col = nhalf * 96 + nt * 16 + ln;
        float b3v = b3[aH + col], nw = hnw[aH + col], nb = hnb[aH + col];
        #pragma unroll
        for (int rg = 0; rg < 4; ++rg) {
            float v = acc3[nt][rg] + b3v + h2f[nt][rg];   // residual from registers (exact)
            h3f[nt][rg] = v * nw + nb;
        }
    }
    __syncthreads();   // all waves done reading h2
    #pragma unroll
    for (int nt = 0; nt < 6; ++nt) {
        int col = nhalf * 96 + nt * 16 + ln;
        #pragma unroll
        for (int rg = 0; rg < 4; ++rg) {
            int ad = (mtile * 16 + quad * 4 + rg) * 200 + col;
            __bf16 h = (__bf16)h3f[nt][rg];
            Hhi[ad] = h;
            Hlo[ad] = (__bf16)(h3f[nt][rg] - (float)h);
        }
    }
    __syncthreads();

    // ---- output layer (K=192, N=16 padded, cols 0..2 real) ----
    if (wv < 4) {
        f32x4 acco = zero;
        const __bf16* W = ws + OW_OFF + a * 3072;
        #pragma unroll 1
        for (int ks = 0; ks < 6; ++ks) {
            int av = (mtile * 16 + ln) * 200 + ks * 32 + quad * 8;
            bf16x8 ah = *(const bf16x8*)&Hhi[av];
            bf16x8 al = *(const bf16x8*)&Hlo[av];
            bf16x8 bw = *(const bf16x8*)&W[ks * 512 + lane * 8];
            acco = MFMA(ah, bw, acco);
            acco = MFMA(al, bw, acco);
        }
        if (ln < O_N) {
            float obv = ob[a * O_N + ln];
            #pragma unroll
            for (int rg = 0; rg < 4; ++rg) {
                int r = row0 + mtile * 16 + quad * 4 + rg;
                out[((size_t)a * B_N + r) * O_N + ln] = acco[rg] + obv;
            }
        }
    }
}

extern "C" void kernel_launch(void* const* d_in, const int* in_sizes, int n_in,
                              void* d_out, int out_size, void* d_ws, size_t ws_size,
                              hipStream_t stream) {
    const float* x   = (const float*)d_in[0];
    const float* inw = (const float*)d_in[1];
    const float* inb = (const float*)d_in[2];
    const float* w1  = (const float*)d_in[3];
    const float* b1  = (const float*)d_in[4];
    const float* w2  = (const float*)d_in[5];
    const float* b2  = (const float*)d_in[6];
    const float* w3  = (const float*)d_in[7];
    const float* b3  = (const float*)d_in[8];
    const float* ow  = (const float*)d_in[9];
    const float* ob  = (const float*)d_in[10];
    const float* s1w = (const float*)d_in[11];
    const float* s1b = (const float*)d_in[12];
    const float* s2w = (const float*)d_in[13];
    const float* s2b = (const float*)d_in[14];
    const float* hnw = (const float*)d_in[15];
    const float* hnb = (const float*)d_in[16];

    __bf16* ws = (__bf16*)d_ws;   // needs 17.7 MB; ws_size assumed sufficient

    prep_kernel<<<dim3((WS_ELEMS + 255) / 256), dim3(256), 0, stream>>>(
        w1, s1w, w2, s2w, w3, ow, ws);

    srek_mfma<<<dim3(A_N * (B_N / 64)), dim3(512), 0, stream>>>(
        x, inw, inb, b1, b2, b3, s1b, s2b, hnw, hnb, ob, ws, (float*)d_out);
}

// Round 3
// 317.681 us; speedup vs baseline: 4.9339x; 1.0165x over previous
//
#include <hip/hip_runtime.h>
#include <math.h>

#define A_N 64
#define B_N 4096
#define D_N 50
#define H_N 192
#define O_N 3

typedef __attribute__((ext_vector_type(8))) __bf16 bf16x8;
typedef __attribute__((ext_vector_type(4))) float f32x4;

// ws layout (bf16 elems), all frag-packed: [a][nt][ks][lane][8]
// frag elem (lane,j) = W[nt*16 + (lane&15)][ks*32 + (lane>>4)*8 + j]
#define W1_OFF   0          // [A][12][2][512]  K=64 (padded from 50)
#define S1_OFF   786432
#define W2_OFF   1572864    // [A][12][6][512]  K=192
#define S2_OFF   3932160
#define W3_OFF   6291456
#define OW_OFF   8650752    // [A][1][6][512]   N=16 (padded from 3), K=192
#define WS_ELEMS 8847360    // *2 bytes = 17.7 MB of d_ws

__device__ __forceinline__ float gelu_exact(float t) {
    return 0.5f * t * (1.0f + erff(t * 0.70710678118654752440f));
}

// One thread per 8-elem fragment row: 2x float4 load (or guarded scalars for K=50),
// one 16B bf16x8 store. 1,105,920 threads total.
__global__ void prep_kernel(const float* __restrict__ w1, const float* __restrict__ s1,
                            const float* __restrict__ w2, const float* __restrict__ s2,
                            const float* __restrict__ w3, const float* __restrict__ ow,
                            __bf16* __restrict__ ws) {
    int idx8 = blockIdx.x * 256 + threadIdx.x;
    if (idx8 >= WS_ELEMS / 8) return;
    int idx = idx8 * 8;
    bf16x8 v;
    if (idx < W2_OFF) {
        // w1/s1: [192][50] -> frag-packed K=64 padded; rows not 16B-aligned -> scalar loads
        const float* src = (idx < S1_OFF) ? w1 : s1;
        int r = (idx < S1_OFF) ? idx : idx - S1_OFF;
        int a = r / 12288;  r %= 12288;
        int nt = r / 1024;  r %= 1024;
        int ks = r / 512;   r %= 512;
        int lane = r >> 3;
        int n = nt * 16 + (lane & 15);
        int k = ks * 32 + (lane >> 4) * 8;
        const float* p = src + (size_t)(a * H_N + n) * D_N + k;
        #pragma unroll
        for (int j = 0; j < 8; ++j)
            v[j] = (k + j < D_N) ? (__bf16)p[j] : (__bf16)0.f;
    } else if (idx < OW_OFF) {
        int r = idx - W2_OFF;
        const float* src = w2;
        if (r >= 4718592)      { src = w3; r -= 4718592; }
        else if (r >= 2359296) { src = s2; r -= 2359296; }
        int a = r / 36864;  r %= 36864;
        int nt = r / 3072;  r %= 3072;
        int ks = r / 512;   r %= 512;
        int lane = r >> 3;
        int n = nt * 16 + (lane & 15);
        int k = ks * 32 + (lane >> 4) * 8;
        const float* p = src + (size_t)(a * H_N + n) * H_N + k;   // 16B-aligned (row=768B, k%8==0)
        f32x4 f0 = *(const f32x4*)p;
        f32x4 f1 = *(const f32x4*)(p + 4);
        #pragma unroll
        for (int j = 0; j < 4; ++j) { v[j] = (__bf16)f0[j]; v[4 + j] = (__bf16)f1[j]; }
    } else {
        int r = idx - OW_OFF;
        int a = r / 3072;   r %= 3072;
        int ks = r / 512;   r %= 512;
        int lane = r >> 3;
        int n = lane & 15;
        int k = ks * 32 + (lane >> 4) * 8;
        if (n < O_N) {
            const float* p = ow + (size_t)(a * O_N + n) * H_N + k;  // 16B-aligned
            f32x4 f0 = *(const f32x4*)p;
            f32x4 f1 = *(const f32x4*)(p + 4);
            #pragma unroll
            for (int j = 0; j < 4; ++j) { v[j] = (__bf16)f0[j]; v[4 + j] = (__bf16)f1[j]; }
        } else {
            #pragma unroll
            for (int j = 0; j < 8; ++j) v[j] = (__bf16)0.f;
        }
    }
    *(bf16x8*)(ws + idx) = v;
}

#define MFMA(a, b, c) __builtin_amdgcn_mfma_f32_16x16x32_bf16((a), (b), (c), 0, 0, 0)

__global__ __launch_bounds__(512, 4)
void srek_mfma(const float* __restrict__ x,
               const float* __restrict__ inw, const float* __restrict__ inb,
               const float* __restrict__ b1,  const float* __restrict__ b2,
               const float* __restrict__ b3,  const float* __restrict__ s1b,
               const float* __restrict__ s2b, const float* __restrict__ hnw,
               const float* __restrict__ hnb, const float* __restrict__ ob,
               const __bf16* __restrict__ ws, float* __restrict__ out) {
    // Activations bf16 [row][k]; residual path (h2) stays fp32 in registers.
    // Pitches: dword-stride mod 32 == 4 -> b128 reads spread across 8 bank-windows.
    __shared__ __bf16 Xhi[64 * 72];    // x_norm, K=64 padded (9.2 KB)
    __shared__ __bf16 Hhi[64 * 200];   // h1 -> h2 -> h3, barrier-reused (25.6 KB)

    const int bid  = blockIdx.x;
    const int slot = bid >> 3;
    const int tile = slot & 63;
    const int a    = ((bid & 7) << 3) | (slot >> 6);   // XCD-aware: agent pinned to XCD
    const int row0 = tile * 64;

    const int tid   = threadIdx.x;
    const int lane  = tid & 63;
    const int wv    = tid >> 6;
    const int mtile = wv & 3;        // 16-row stripe
    const int nhalf = wv >> 2;       // 96-col half
    const int ln    = lane & 15;
    const int quad  = lane >> 4;
    const int aH    = a * H_N;

    // ---- stage x_norm = x*inw + inb (fp32 math, bf16 store) ----
    for (int e = tid; e < 64 * 64; e += 512) {
        int r = e >> 6, k = e & 63;
        float v = 0.f;
        if (k < D_N) v = x[(size_t)(row0 + r) * D_N + k] * inw[a * D_N + k] + inb[a * D_N + k];
        Xhi[r * 72 + k] = (__bf16)v;
    }
    __syncthreads();

    const f32x4 zero = {0.f, 0.f, 0.f, 0.f};
    f32x4 accT[6], accS[6];

    // ---- layer1 + skip1 (K=64) ----
    #pragma unroll
    for (int i = 0; i < 6; ++i) { accT[i] = zero; accS[i] = zero; }
    {
        const __bf16* W = ws + W1_OFF + a * 12288;
        const __bf16* S = ws + S1_OFF + a * 12288;
        #pragma unroll
        for (int ks = 0; ks < 2; ++ks) {
            int av = (mtile * 16 + ln) * 72 + ks * 32 + quad * 8;
            bf16x8 ah = *(const bf16x8*)&Xhi[av];
            #pragma unroll
            for (int nt = 0; nt < 6; ++nt) {
                int fo = ((nhalf * 6 + nt) * 2 + ks) * 512 + lane * 8;
                bf16x8 bw = *(const bf16x8*)&W[fo];
                bf16x8 bs = *(const bf16x8*)&S[fo];
                accT[nt] = MFMA(ah, bw, accT[nt]);
                accS[nt] = MFMA(ah, bs, accS[nt]);
            }
        }
    }
    // h1 = gelu(T + b1) + S + s1b  -> Hhi (fresh region, disjoint per wave)
    #pragma unroll
    for (int nt = 0; nt < 6; ++nt) {
        int col = nhalf * 96 + nt * 16 + ln;
        float bb = b1[aH + col], sb = s1b[aH + col];
        #pragma unroll
        for (int rg = 0; rg < 4; ++rg) {
            float v = gelu_exact(accT[nt][rg] + bb) + accS[nt][rg] + sb;
            Hhi[(mtile * 16 + quad * 4 + rg) * 200 + col] = (__bf16)v;
        }
    }
    __syncthreads();

    // ---- layer2 + skip2 (K=192) ----
    #pragma unroll
    for (int i = 0; i < 6; ++i) { accT[i] = zero; accS[i] = zero; }
    {
        const __bf16* W = ws + W2_OFF + a * 36864;
        const __bf16* S = ws + S2_OFF + a * 36864;
        #pragma unroll 1
        for (int ks = 0; ks < 6; ++ks) {
            int av = (mtile * 16 + ln) * 200 + ks * 32 + quad * 8;
            bf16x8 ah = *(const bf16x8*)&Hhi[av];
            #pragma unroll
            for (int nt = 0; nt < 6; ++nt) {
                int fo = ((nhalf * 6 + nt) * 6 + ks) * 512 + lane * 8;
                bf16x8 bw = *(const bf16x8*)&W[fo];
                bf16x8 bs = *(const bf16x8*)&S[fo];
                accT[nt] = MFMA(ah, bw, accT[nt]);
                accS[nt] = MFMA(ah, bs, accS[nt]);
            }
        }
    }
    f32x4 h2f[6];   // fp32 residual kept in registers (precision-critical)
    #pragma unroll
    for (int nt = 0; nt < 6; ++nt) {
        int col = nhalf * 96 + nt * 16 + ln;
        float bb = b2[aH + col], sb = s2b[aH + col];
        #pragma unroll
        for (int rg = 0; rg < 4; ++rg)
            h2f[nt][rg] = gelu_exact(accT[nt][rg] + bb) + accS[nt][rg] + sb;
    }
    __syncthreads();   // all waves done reading h1
    #pragma unroll
    for (int nt = 0; nt < 6; ++nt) {
        int col = nhalf * 96 + nt * 16 + ln;
        #pragma unroll
        for (int rg = 0; rg < 4; ++rg)
            Hhi[(mtile * 16 + quad * 4 + rg) * 200 + col] = (__bf16)h2f[nt][rg];
    }
    __syncthreads();

    // ---- layer3 (K=192) + residual + hidden_norm ----
    f32x4 acc3[6];
    #pragma unroll
    for (int i = 0; i < 6; ++i) acc3[i] = zero;
    {
        const __bf16* W = ws + W3_OFF + a * 36864;
        #pragma unroll 1
        for (int ks = 0; ks < 6; ++ks) {
            int av = (mtile * 16 + ln) * 200 + ks * 32 + quad * 8;
            bf16x8 ah = *(const bf16x8*)&Hhi[av];
            #pragma unroll
            for (int nt = 0; nt < 6; ++nt) {
                int fo = ((nhalf * 6 + nt) * 6 + ks) * 512 + lane * 8;
                bf16x8 bw = *(const bf16x8*)&W[fo];
                acc3[nt] = MFMA(ah, bw, acc3[nt]);
            }
        }
    }
    f32x4 h3f[6];
    #pragma unroll
    for (int nt = 0; nt < 6; ++nt) {
        int col = nhalf * 96 + nt * 16 + ln;
        float b3v = b3[aH + col], nw = hnw[aH + col], nb = hnb[aH + col];
        #pragma unroll
        for (int rg = 0; rg < 4; ++rg) {
            float v = acc3[nt][rg] + b3v + h2f[nt][rg];   // residual from fp32 registers
            h3f[nt][rg] = v * nw + nb;
        }
    }
    __syncthreads();   // all waves done reading h2
    #pragma unroll
    for (int nt = 0; nt < 6; ++nt) {
        int col = nhalf * 96 + nt * 16 + ln;
        #pragma unroll
        for (int rg = 0; rg < 4; ++rg)
            Hhi[(mtile * 16 + quad * 4 + rg) * 200 + col] = (__bf16)h3f[nt][rg];
    }
    __syncthreads();

    // ---- output layer (K=192, N=16 padded, cols 0..2 real) ----
    if (wv < 4) {
        f32x4 acco = zero;
        const __bf16* W = ws + OW_OFF + a * 3072;
        #pragma unroll 1
        for (int ks = 0; ks < 6; ++ks) {
            int av = (mtile * 16 + ln) * 200 + ks * 32 + quad * 8;
            bf16x8 ah = *(const bf16x8*)&Hhi[av];
            bf16x8 bw = *(const bf16x8*)&W[ks * 512 + lane * 8];
            acco = MFMA(ah, bw, acco);
        }
        if (ln < O_N) {
            float obv = ob[a * O_N + ln];
            #pragma unroll
            for (int rg = 0; rg < 4; ++rg) {
                int r = row0 + mtile * 16 + quad * 4 + rg;
                out[((size_t)a * B_N + r) * O_N + ln] = acco[rg] + obv;
            }
        }
    }
}

extern "C" void kernel_launch(void* const* d_in, const int* in_sizes, int n_in,
                              void* d_out, int out_size, void* d_ws, size_t ws_size,
                              hipStream_t stream) {
    const float* x   = (const float*)d_in[0];
    const float* inw = (const float*)d_in[1];
    const float* inb = (const float*)d_in[2];
    const float* w1  = (const float*)d_in[3];
    const float* b1  = (const float*)d_in[4];
    const float* w2  = (const float*)d_in[5];
    const float* b2  = (const float*)d_in[6];
    const float* w3  = (const float*)d_in[7];
    const float* b3  = (const float*)d_in[8];
    const float* ow  = (const float*)d_in[9];
    const float* ob  = (const float*)d_in[10];
    const float* s1w = (const float*)d_in[11];
    const float* s1b = (const float*)d_in[12];
    const float* s2w = (const float*)d_in[13];
    const float* s2b = (const float*)d_in[14];
    const float* hnw = (const float*)d_in[15];
    const float* hnb = (const float*)d_in[16];

    __bf16* ws = (__bf16*)d_ws;   // 17.7 MB of d_ws

    prep_kernel<<<dim3((WS_ELEMS / 8 + 255) / 256), dim3(256), 0, stream>>>(
        w1, s1w, w2, s2w, w3, ow, ws);

    srek_mfma<<<dim3(A_N * (B_N / 64)), dim3(512), 0, stream>>>(
        x, inw, inb, b1, b2, b3, s1b, s2b, hnw, hnb, ob, ws, (float*)d_out);
}

// Round 4
// 263.078 us; speedup vs baseline: 5.9580x; 1.2076x over previous
//
#include <hip/hip_runtime.h>
#include <math.h>

#define A_N 64
#define B_N 4096
#define D_N 50
#define H_N 192
#define O_N 3

typedef __attribute__((ext_vector_type(8))) __bf16 bf16x8;
typedef __attribute__((ext_vector_type(4))) float f32x4;

// ws layout (bf16 elems), all frag-packed: [a][nt][ks][lane][8]
// frag elem (lane,j) = W[nt*16 + (lane&15)][ks*32 + (lane>>4)*8 + j]
#define W1_OFF   0          // [A][12][2][512]  K=64 (padded from 50)
#define S1_OFF   786432
#define W2_OFF   1572864    // [A][12][6][512]  K=192
#define S2_OFF   3932160
#define W3_OFF   6291456
#define OW_OFF   8650752    // [A][1][6][512]   N=16 (padded from 3), K=192
#define WS_ELEMS 8847360    // *2 bytes = 17.7 MB of d_ws

#if __has_builtin(__builtin_amdgcn_rcpf)
#define FRCP(x) __builtin_amdgcn_rcpf(x)
#else
#define FRCP(x) (1.0f / (x))
#endif
#if __has_builtin(__builtin_amdgcn_exp2f)
#define FEXP2(x) __builtin_amdgcn_exp2f(x)
#else
#define FEXP2(x) exp2f(x)
#endif

// fast exact-enough gelu: A&S 7.1.26 erf (|eps| <= 1.5e-7) + native rcp/exp2
__device__ __forceinline__ float gelu_f(float xx) {
    float t  = 0.70710678118654752440f * xx;
    float at = fabsf(t);
    float k  = FRCP(fmaf(0.3275911f, at, 1.0f));
    float p  = fmaf(k, 1.061405429f, -1.453152027f);
    p = fmaf(k, p, 1.421413741f);
    p = fmaf(k, p, -0.284496736f);
    p = fmaf(k, p, 0.254829592f);
    p = p * k;
    float e  = FEXP2(t * t * -1.44269504088896340736f);
    float er = fmaf(-p, e, 1.0f);            // erf(|t|)
    er = (t < 0.f) ? -er : er;
    return 0.5f * xx * (1.0f + er);
}

// One thread per 8-elem fragment row: vectorized loads, one 16B bf16x8 store.
__global__ void prep_kernel(const float* __restrict__ w1, const float* __restrict__ s1,
                            const float* __restrict__ w2, const float* __restrict__ s2,
                            const float* __restrict__ w3, const float* __restrict__ ow,
                            __bf16* __restrict__ ws) {
    int idx8 = blockIdx.x * 256 + threadIdx.x;
    if (idx8 >= WS_ELEMS / 8) return;
    int idx = idx8 * 8;
    bf16x8 v;
    if (idx < W2_OFF) {
        const float* src = (idx < S1_OFF) ? w1 : s1;
        int r = (idx < S1_OFF) ? idx : idx - S1_OFF;
        int a = r / 12288;  r %= 12288;
        int nt = r / 1024;  r %= 1024;
        int ks = r / 512;   r %= 512;
        int lane = r >> 3;
        int n = nt * 16 + (lane & 15);
        int k = ks * 32 + (lane >> 4) * 8;
        const float* p = src + (size_t)(a * H_N + n) * D_N + k;
        #pragma unroll
        for (int j = 0; j < 8; ++j)
            v[j] = (k + j < D_N) ? (__bf16)p[j] : (__bf16)0.f;
    } else if (idx < OW_OFF) {
        int r = idx - W2_OFF;
        const float* src = w2;
        if (r >= 4718592)      { src = w3; r -= 4718592; }
        else if (r >= 2359296) { src = s2; r -= 2359296; }
        int a = r / 36864;  r %= 36864;
        int nt = r / 3072;  r %= 3072;
        int ks = r / 512;   r %= 512;
        int lane = r >> 3;
        int n = nt * 16 + (lane & 15);
        int k = ks * 32 + (lane >> 4) * 8;
        const float* p = src + (size_t)(a * H_N + n) * H_N + k;
        f32x4 f0 = *(const f32x4*)p;
        f32x4 f1 = *(const f32x4*)(p + 4);
        #pragma unroll
        for (int j = 0; j < 4; ++j) { v[j] = (__bf16)f0[j]; v[4 + j] = (__bf16)f1[j]; }
    } else {
        int r = idx - OW_OFF;
        int a = r / 3072;   r %= 3072;
        int ks = r / 512;   r %= 512;
        int lane = r >> 3;
        int n = lane & 15;
        int k = ks * 32 + (lane >> 4) * 8;
        if (n < O_N) {
            const float* p = ow + (size_t)(a * O_N + n) * H_N + k;
            f32x4 f0 = *(const f32x4*)p;
            f32x4 f1 = *(const f32x4*)(p + 4);
            #pragma unroll
            for (int j = 0; j < 4; ++j) { v[j] = (__bf16)f0[j]; v[4 + j] = (__bf16)f1[j]; }
        } else {
            #pragma unroll
            for (int j = 0; j < 8; ++j) v[j] = (__bf16)0.f;
        }
    }
    *(bf16x8*)(ws + idx) = v;
}

#define MFMA(a, b, c) __builtin_amdgcn_mfma_f32_16x16x32_bf16((a), (b), (c), 0, 0, 0)

// Block = 1 agent x 64 rows, 256 threads (4 waves). Wave wv owns cols [wv*48, wv*48+48)
// (3 nt-tiles) for ALL 4 row-mtiles -> every LDS B-fragment read by exactly one wave.
// Weights staged to LDS once per ks-chunk; register-prefetch software pipeline.
__global__ __launch_bounds__(256, 2)
void srek_mfma(const float* __restrict__ x,
               const float* __restrict__ inw, const float* __restrict__ inb,
               const float* __restrict__ b1,  const float* __restrict__ b2,
               const float* __restrict__ b3,  const float* __restrict__ s1b,
               const float* __restrict__ s2b, const float* __restrict__ hnw,
               const float* __restrict__ hnb, const float* __restrict__ ob,
               const __bf16* __restrict__ ws, float* __restrict__ out) {
    __shared__ __bf16 Xs[64 * 72];    // x_norm, K=64 padded (9.2 KB)
    __shared__ __bf16 Hs[64 * 200];   // h1 -> h2 -> h3, barrier-reused (25.6 KB)
    __shared__ __bf16 Bs[24 * 512];   // weight frags, frag f at f*512 (24.6 KB)
                                      // dual layers: f = ts*12 + nt (ts 0=W,1=S); L3: f = nt

    const int bid  = blockIdx.x;
    const int slot = bid >> 3;
    const int tile = slot & 63;
    const int a    = ((bid & 7) << 3) | (slot >> 6);   // agent pinned to XCD
    const int row0 = tile * 64;

    const int tid  = threadIdx.x;
    const int lane = tid & 63;
    const int wv   = tid >> 6;     // 0..3: col-quarter
    const int ln   = lane & 15;
    const int quad = lane >> 4;
    const int aH   = a * H_N;
    const int c0   = wv * 48;
    const int l8   = lane * 8;
    const int f6   = wv * 6;       // frag base, 24-frag chunks
    const int f3   = wv * 3;       // frag base, 12-frag chunks

    const __bf16* W1 = ws + W1_OFF + a * 12288;
    const __bf16* S1 = ws + S1_OFF + a * 12288;
    const __bf16* W2 = ws + W2_OFF + a * 36864;
    const __bf16* S2 = ws + S2_OFF + a * 36864;
    const __bf16* W3 = ws + W3_OFF + a * 36864;
    const __bf16* OWp= ws + OW_OFF + a * 3072;

    bf16x8 pf[6];
    f32x4 accT[12], accS[12], h2f[12];
    const f32x4 zero = {0.f, 0.f, 0.f, 0.f};

    // ---- prefetch L1 ks0 chunk (24 frags, 6/wave) ----
    #pragma unroll
    for (int i = 0; i < 6; ++i) {
        int f = f6 + i; int nt = f % 12;
        const __bf16* base = (f < 12) ? W1 : S1;
        pf[i] = *(const bf16x8*)(base + (nt * 2 + 0) * 512 + l8);
    }

    // ---- x_norm -> Xs (overlaps prefetch latency) ----
    for (int e = tid; e < 64 * 64; e += 256) {
        int r = e >> 6, k = e & 63;
        float v = 0.f;
        if (k < D_N) v = x[(size_t)(row0 + r) * D_N + k] * inw[a * D_N + k] + inb[a * D_N + k];
        Xs[r * 72 + k] = (__bf16)v;
    }

    auto stage24 = [&]() {
        #pragma unroll
        for (int i = 0; i < 6; ++i) *(bf16x8*)(Bs + (f6 + i) * 512 + l8) = pf[i];
    };
    auto stage12 = [&]() {
        #pragma unroll
        for (int i = 0; i < 3; ++i) *(bf16x8*)(Bs + (f3 + i) * 512 + l8) = pf[i];
    };
    auto pf24 = [&](const __bf16* Wb, const __bf16* Sb, int KS, int ks) {
        #pragma unroll
        for (int i = 0; i < 6; ++i) {
            int f = f6 + i; int nt = f % 12;
            const __bf16* base = (f < 12) ? Wb : Sb;
            pf[i] = *(const bf16x8*)(base + (nt * KS + ks) * 512 + l8);
        }
    };
    auto pf12 = [&](int ks) {
        #pragma unroll
        for (int i = 0; i < 3; ++i)
            pf[i] = *(const bf16x8*)(W3 + ((f3 + i) * 6 + ks) * 512 + l8);
    };
    auto compute_dual = [&](const __bf16* As, int pitch, int ks) {
        bf16x8 bw[3], bs2[3];
        #pragma unroll
        for (int t = 0; t < 3; ++t) {
            bw[t]  = *(const bf16x8*)(Bs + (wv * 3 + t) * 512 + l8);
            bs2[t] = *(const bf16x8*)(Bs + (12 + wv * 3 + t) * 512 + l8);
        }
        #pragma unroll
        for (int mt = 0; mt < 4; ++mt) {
            bf16x8 av = *(const bf16x8*)(As + (mt * 16 + ln) * pitch + ks * 32 + quad * 8);
            #pragma unroll
            for (int t = 0; t < 3; ++t) {
                accT[mt * 3 + t] = MFMA(av, bw[t],  accT[mt * 3 + t]);
                accS[mt * 3 + t] = MFMA(av, bs2[t], accS[mt * 3 + t]);
            }
        }
    };
    auto compute_single = [&](int ks) {
        bf16x8 bw[3];
        #pragma unroll
        for (int t = 0; t < 3; ++t)
            bw[t] = *(const bf16x8*)(Bs + (wv * 3 + t) * 512 + l8);
        #pragma unroll
        for (int mt = 0; mt < 4; ++mt) {
            bf16x8 av = *(const bf16x8*)(Hs + (mt * 16 + ln) * 200 + ks * 32 + quad * 8);
            #pragma unroll
            for (int t = 0; t < 3; ++t)
                accT[mt * 3 + t] = MFMA(av, bw[t], accT[mt * 3 + t]);
        }
    };

    #pragma unroll
    for (int i = 0; i < 12; ++i) { accT[i] = zero; accS[i] = zero; }

    // ================= layer1 + skip1 (K=64, 2 ks-chunks) =================
    stage24();                 // Bs <- L1 ks0
    pf24(W1, S1, 2, 1);        // pf <- L1 ks1
    __syncthreads();           // Bs + Xs ready
    compute_dual(Xs, 72, 0);
    __syncthreads();           // all waves done reading Bs(ks0)
    stage24();                 // Bs <- L1 ks1
    pf24(W2, S2, 6, 0);        // pf <- L2 ks0
    __syncthreads();
    compute_dual(Xs, 72, 1);

    // epilogue L1 -> Hs (fresh region, no barrier needed before writes)
    #pragma unroll
    for (int t = 0; t < 3; ++t) {
        int col = c0 + t * 16 + ln;
        float bb = b1[aH + col], sb = s1b[aH + col];
        #pragma unroll
        for (int mt = 0; mt < 4; ++mt) {
            f32x4 vT = accT[mt * 3 + t], vS = accS[mt * 3 + t];
            #pragma unroll
            for (int rg = 0; rg < 4; ++rg) {
                float v = gelu_f(vT[rg] + bb) + vS[rg] + sb;
                Hs[(mt * 16 + quad * 4 + rg) * 200 + col] = (__bf16)v;
            }
        }
    }
    #pragma unroll
    for (int i = 0; i < 12; ++i) { accT[i] = zero; accS[i] = zero; }
    __syncthreads();           // done reading Bs(L1ks1); Hs(h1) ready
    stage24();                 // Bs <- L2 ks0
    pf24(W2, S2, 6, 1);        // pf <- L2 ks1
    __syncthreads();

    // ================= layer2 + skip2 (K=192, 6 ks-chunks) =================
    #pragma unroll 1
    for (int ks = 0; ks < 5; ++ks) {
        compute_dual(Hs, 200, ks);
        __syncthreads();       // done reading Bs(ks)
        stage24();             // Bs <- ks+1
        if (ks < 4) pf24(W2, S2, 6, ks + 2);
        else        pf12(0);   // pf <- L3 ks0
        __syncthreads();
    }
    compute_dual(Hs, 200, 5);
    // h2 (fp32) kept in registers; VALU before the barrier
    #pragma unroll
    for (int t = 0; t < 3; ++t) {
        int col = c0 + t * 16 + ln;
        float bb = b2[aH + col], sb = s2b[aH + col];
        #pragma unroll
        for (int mt = 0; mt < 4; ++mt) {
            #pragma unroll
            for (int rg = 0; rg < 4; ++rg)
                h2f[mt * 3 + t][rg] = gelu_f(accT[mt * 3 + t][rg] + bb) + accS[mt * 3 + t][rg] + sb;
        }
    }
    #pragma unroll
    for (int i = 0; i < 12; ++i) accT[i] = zero;
    __syncthreads();           // all waves done reading Bs(ks5) and Hs(h1)
    stage12();                 // Bs <- L3 ks0
    #pragma unroll
    for (int t = 0; t < 3; ++t) {
        int col = c0 + t * 16 + ln;
        #pragma unroll
        for (int mt = 0; mt < 4; ++mt)
            #pragma unroll
            for (int rg = 0; rg < 4; ++rg)
                Hs[(mt * 16 + quad * 4 + rg) * 200 + col] = (__bf16)h2f[mt * 3 + t][rg];
    }
    pf12(1);                   // pf <- L3 ks1
    __syncthreads();

    // ================= layer3 (K=192, single matrix) =================
    #pragma unroll 1
    for (int ks = 0; ks < 5; ++ks) {
        compute_single(ks);
        __syncthreads();
        stage12();             // Bs <- ks+1
        if (ks < 4) pf12(ks + 2);
        __syncthreads();
    }
    compute_single(5);

    // OW frags direct from global (tiny; latency hidden by epilogue VALU)
    bf16x8 owf[6];
    #pragma unroll
    for (int ks = 0; ks < 6; ++ks)
        owf[ks] = *(const bf16x8*)(OWp + ks * 512 + l8);

    // h3 = (acc3 + b3 + h2) * hnw + hnb   (VALU before barrier)
    #pragma unroll
    for (int t = 0; t < 3; ++t) {
        int col = c0 + t * 16 + ln;
        float b3v = b3[aH + col], nw = hnw[aH + col], nb = hnb[aH + col];
        #pragma unroll
        for (int mt = 0; mt < 4; ++mt)
            #pragma unroll
            for (int rg = 0; rg < 4; ++rg)
                h2f[mt * 3 + t][rg] = (accT[mt * 3 + t][rg] + b3v + h2f[mt * 3 + t][rg]) * nw + nb;
    }
    __syncthreads();           // all waves done reading Hs(h2)
    #pragma unroll
    for (int t = 0; t < 3; ++t) {
        int col = c0 + t * 16 + ln;
        #pragma unroll
        for (int mt = 0; mt < 4; ++mt)
            #pragma unroll
            for (int rg = 0; rg < 4; ++rg)
                Hs[(mt * 16 + quad * 4 + rg) * 200 + col] = (__bf16)h2f[mt * 3 + t][rg];
    }
    __syncthreads();           // Hs(h3) ready

    // ================= output layer (wave wv = row-mtile wv) =================
    {
        f32x4 acco = zero;
        #pragma unroll
        for (int ks = 0; ks < 6; ++ks) {
            bf16x8 av = *(const bf16x8*)(Hs + (wv * 16 + ln) * 200 + ks * 32 + quad * 8);
            acco = MFMA(av, owf[ks], acco);
        }
        if (ln < O_N) {
            float obv = ob[a * O_N + ln];
            #pragma unroll
            for (int rg = 0; rg < 4; ++rg) {
                int r = row0 + wv * 16 + quad * 4 + rg;
                out[((size_t)a * B_N + r) * O_N + ln] = acco[rg] + obv;
            }
        }
    }
}

extern "C" void kernel_launch(void* const* d_in, const int* in_sizes, int n_in,
                              void* d_out, int out_size, void* d_ws, size_t ws_size,
                              hipStream_t stream) {
    const float* x   = (const float*)d_in[0];
    const float* inw = (const float*)d_in[1];
    const float* inb = (const float*)d_in[2];
    const float* w1  = (const float*)d_in[3];
    const float* b1  = (const float*)d_in[4];
    const float* w2  = (const float*)d_in[5];
    const float* b2  = (const float*)d_in[6];
    const float* w3  = (const float*)d_in[7];
    const float* b3  = (const float*)d_in[8];
    const float* ow  = (const float*)d_in[9];
    const float* ob  = (const float*)d_in[10];
    const float* s1w = (const float*)d_in[11];
    const float* s1b = (const float*)d_in[12];
    const float* s2w = (const float*)d_in[13];
    const float* s2b = (const float*)d_in[14];
    const float* hnw = (const float*)d_in[15];
    const float* hnb = (const float*)d_in[16];

    __bf16* ws = (__bf16*)d_ws;   // 17.7 MB of d_ws

    prep_kernel<<<dim3((WS_ELEMS / 8 + 255) / 256), dim3(256), 0, stream>>>(
        w1, s1w, w2, s2w, w3, ow, ws);

    srek_mfma<<<dim3(A_N * (B_N / 64)), dim3(256), 0, stream>>>(
        x, inw, inb, b1, b2, b3, s1b, s2b, hnw, hnb, ob, ws, (float*)d_out);
}

// Round 5
// 246.483 us; speedup vs baseline: 6.3591x; 1.0673x over previous
//
#include <hip/hip_runtime.h>
#include <math.h>

#define A_N 64
#define B_N 4096
#define D_N 50
#define H_N 192
#define O_N 3

typedef __attribute__((ext_vector_type(8))) __bf16 bf16x8;
typedef __attribute__((ext_vector_type(4))) __bf16 bf16x4;
typedef __attribute__((ext_vector_type(4))) float f32x4;

// ws layout (bf16 elems), frag-packed: frag elem (lane,j) = W[nt*16+(lane&15)][ks*32+(lane>>4)*8+j]
#define W1_OFF   0          // [A][12 nt][2 ks][512]   K=64 (padded from 50)
#define S1_OFF   786432
#define W2_OFF   1572864    // [A][12 nt][6 ks][512]   K=192
#define S2_OFF   3932160
#define W3_OFF   6291456
#define OW_OFF   8650752    // [A][6 ks][512]          N=16 (padded from 3), K=192
#define WS_ELEMS 8847360    // *2 B = 17.7 MB of d_ws

#if __has_builtin(__builtin_amdgcn_rcpf)
#define FRCP(x) __builtin_amdgcn_rcpf(x)
#else
#define FRCP(x) (1.0f / (x))
#endif
#if __has_builtin(__builtin_amdgcn_exp2f)
#define FEXP2(x) __builtin_amdgcn_exp2f(x)
#else
#define FEXP2(x) exp2f(x)
#endif

// A&S 7.1.26 erf (|eps|<=1.5e-7) + native rcp/exp2
__device__ __forceinline__ float gelu_f(float xx) {
    float t  = 0.70710678118654752440f * xx;
    float at = fabsf(t);
    float k  = FRCP(fmaf(0.3275911f, at, 1.0f));
    float p  = fmaf(k, 1.061405429f, -1.453152027f);
    p = fmaf(k, p, 1.421413741f);
    p = fmaf(k, p, -0.284496736f);
    p = fmaf(k, p, 0.254829592f);
    p = p * k;
    float e  = FEXP2(t * t * -1.44269504088896340736f);
    float er = fmaf(-p, e, 1.0f);
    er = (t < 0.f) ? -er : er;
    return 0.5f * xx * (1.0f + er);
}

// Prep v2: coalesced loads -> LDS transpose -> coalesced frag writes.
// Grid: [0,384) big matrices (w2/s2/w3, 2 blocks per agent-matrix),
//       [384,512) w1/s1 (1 block per agent-matrix), [512,524) ow.
__global__ __launch_bounds__(256)
void prep_kernel(const float* __restrict__ w1, const float* __restrict__ s1,
                 const float* __restrict__ w2, const float* __restrict__ s2,
                 const float* __restrict__ w3, const float* __restrict__ ow,
                 __bf16* __restrict__ ws) {
    __shared__ __bf16 T[192 * 72];   // also used as [32][200] in section A
    const int b   = blockIdx.x;
    const int tid = threadIdx.x;

    if (b < 384) {
        int m = b / 128;                  // 0=w2 1=s2 2=w3
        int r = b % 128; int a = r >> 1; int half = r & 1;
        const float* src = ((m == 0) ? w2 : (m == 1) ? s2 : w3) + (size_t)a * 36864;
        __bf16* dst = ws + ((m == 0) ? W2_OFF : (m == 1) ? S2_OFF : W3_OFF) + (size_t)a * 36864;
        for (int rc = half * 3; rc < half * 3 + 3; ++rc) {
            #pragma unroll
            for (int i = 0; i < 6; ++i) {                 // 1536 float4 = 32 rows x 192 cols
                int f4 = i * 256 + tid;
                int row = f4 / 48, kc = (f4 % 48) * 4;
                f32x4 v = *(const f32x4*)(src + (size_t)(rc * 32 + row) * 192 + kc);
                bf16x4 o;
                #pragma unroll
                for (int j = 0; j < 4; ++j) o[j] = (__bf16)v[j];
                *(bf16x4*)(T + row * 200 + kc) = o;       // pitch 200: 2-way max
            }
            __syncthreads();
            #pragma unroll
            for (int i = 0; i < 3; ++i) {                 // 768 frag-rows (2 nt x 6 ks x 64)
                int fr = i * 256 + tid;
                int f = fr >> 6, lane = fr & 63;
                int ntl = f / 6, ks = f % 6;
                int n = ntl * 16 + (lane & 15), k = ks * 32 + (lane >> 4) * 8;
                bf16x8 v = *(const bf16x8*)(T + n * 200 + k);
                *(bf16x8*)(dst + ((size_t)(rc * 2 + ntl) * 6 + ks) * 512 + lane * 8) = v;
            }
            __syncthreads();
        }
    } else if (b < 512) {
        int r = b - 384; int m = r >> 6; int a = r & 63;
        const float* src = (m ? s1 : w1) + (size_t)a * 9600;
        __bf16* dst = ws + (m ? S1_OFF : W1_OFF) + (size_t)a * 12288;
        for (int e = tid; e < 192 * 72; e += 256) T[e] = (__bf16)0.f;
        __syncthreads();
        for (int e = tid; e < 9600; e += 256) {
            int row = e / 50, k = e - row * 50;
            T[row * 72 + k] = (__bf16)src[e];
        }
        __syncthreads();
        #pragma unroll
        for (int i = 0; i < 6; ++i) {                     // 1536 frag-rows (12 nt x 2 ks x 64)
            int fr = i * 256 + tid;
            int f = fr >> 6, lane = fr & 63;
            int nt = f >> 1, ks = f & 1;
            int n = nt * 16 + (lane & 15), k = ks * 32 + (lane >> 4) * 8;
            bf16x8 v = *(const bf16x8*)(T + n * 72 + k);
            *(bf16x8*)(dst + (size_t)(nt * 2 + ks) * 512 + lane * 8) = v;
        }
    } else {
        int r = b - 512;
        #pragma unroll
        for (int i = 0; i < 8; ++i) {                     // 24576 frag-rows total
            int fr = (r * 8 + i) * 256 + tid;
            int a = fr / 384, rem = fr - a * 384;
            int ks = rem >> 6, lane = rem & 63;
            int n = lane & 15, k = ks * 32 + (lane >> 4) * 8;
            bf16x8 v;
            if (n < O_N) {
                const float* p = ow + ((size_t)a * O_N + n) * H_N + k;
                f32x4 f0 = *(const f32x4*)p, f1 = *(const f32x4*)(p + 4);
                #pragma unroll
                for (int j = 0; j < 4; ++j) { v[j] = (__bf16)f0[j]; v[4 + j] = (__bf16)f1[j]; }
            } else {
                #pragma unroll
                for (int j = 0; j < 8; ++j) v[j] = (__bf16)0.f;
            }
            *(bf16x8*)(ws + OW_OFF + (size_t)a * 3072 + ks * 512 + lane * 8) = v;
        }
    }
}

// Operand-swapped MFMA: weights = A, activations = B.
// D: col(m, weight-col) = quad*4+reg, row(n, batch-row) = lane&15.
#define MFMA(a, b, c) __builtin_amdgcn_mfma_f32_16x16x32_bf16((a), (b), (c), 0, 0, 0)

__global__ __launch_bounds__(256, 3)
void srek_mfma(const float* __restrict__ x,
               const float* __restrict__ inw, const float* __restrict__ inb,
               const float* __restrict__ b1,  const float* __restrict__ b2,
               const float* __restrict__ b3,  const float* __restrict__ s1b,
               const float* __restrict__ s2b, const float* __restrict__ hnw,
               const float* __restrict__ hnb, const float* __restrict__ ob,
               const __bf16* __restrict__ ws, float* __restrict__ out) {
    __shared__ __bf16 Xs[64 * 72];    // x_norm (9.2 KB)
    __shared__ __bf16 Hs[64 * 200];   // h1 -> h2 -> h3 (25.6 KB); total 34.8 KB

    const int bid  = blockIdx.x;
    const int slot = bid >> 3;
    const int tile = slot & 63;
    const int a    = ((bid & 7) << 3) | (slot >> 6);   // agent pinned to XCD
    const int row0 = tile * 64;

    const int tid  = threadIdx.x;
    const int lane = tid & 63;
    const int wv   = tid >> 6;     // col-quarter
    const int ln   = lane & 15;
    const int quad = lane >> 4;
    const int aH   = a * H_N;
    const int c0   = wv * 48;
    const int l8   = lane * 8;
    const int f3   = wv * 3;       // this wave's nt base (3 disjoint col-tiles)

    const __bf16* W1 = ws + W1_OFF + (size_t)a * 12288;
    const __bf16* S1 = ws + S1_OFF + (size_t)a * 12288;
    const __bf16* W2 = ws + W2_OFF + (size_t)a * 36864;
    const __bf16* S2 = ws + S2_OFF + (size_t)a * 36864;
    const __bf16* W3 = ws + W3_OFF + (size_t)a * 36864;
    const __bf16* OWp= ws + OW_OFF + (size_t)a * 3072;

    bf16x8 nxt[6];
    f32x4 accT[12], accS[12], h2f[12];
    const f32x4 zero = {0.f, 0.f, 0.f, 0.f};

    // prefetch L1 ks0 (this wave's 3 W + 3 S frags)
    #pragma unroll
    for (int t = 0; t < 3; ++t) {
        nxt[t]     = *(const bf16x8*)(W1 + ((f3 + t) * 2 + 0) * 512 + l8);
        nxt[3 + t] = *(const bf16x8*)(S1 + ((f3 + t) * 2 + 0) * 512 + l8);
    }

    // x_norm -> Xs (hides prefetch latency)
    for (int e = tid; e < 64 * 64; e += 256) {
        int r = e >> 6, k = e & 63;
        float v = 0.f;
        if (k < D_N) v = x[(size_t)(row0 + r) * D_N + k] * inw[a * D_N + k] + inb[a * D_N + k];
        Xs[r * 72 + k] = (__bf16)v;
    }

    auto compute_dual = [&](const __bf16* As, int pitch, int ks,
                            const bf16x8* cw, const bf16x8* cs) {
        #pragma unroll
        for (int mt = 0; mt < 4; ++mt) {
            bf16x8 av = *(const bf16x8*)(As + (mt * 16 + ln) * pitch + ks * 32 + quad * 8);
            #pragma unroll
            for (int t = 0; t < 3; ++t) {
                accT[mt * 3 + t] = MFMA(cw[t], av, accT[mt * 3 + t]);
                accS[mt * 3 + t] = MFMA(cs[t], av, accS[mt * 3 + t]);
            }
        }
    };
    auto compute_single = [&](int ks, const bf16x8* cw) {
        #pragma unroll
        for (int mt = 0; mt < 4; ++mt) {
            bf16x8 av = *(const bf16x8*)(Hs + (mt * 16 + ln) * 200 + ks * 32 + quad * 8);
            #pragma unroll
            for (int t = 0; t < 3; ++t)
                accT[mt * 3 + t] = MFMA(cw[t], av, accT[mt * 3 + t]);
        }
    };

    #pragma unroll
    for (int i = 0; i < 12; ++i) { accT[i] = zero; accS[i] = zero; }
    __syncthreads();                                   // B1: Xs ready

    // ================= layer1 + skip1 (K=64, 2 chunks) =================
    {
        bf16x8 cw[3], cs[3];
        #pragma unroll
        for (int t = 0; t < 3; ++t) { cw[t] = nxt[t]; cs[t] = nxt[3 + t]; }
        #pragma unroll
        for (int t = 0; t < 3; ++t) {                  // prefetch L1 ks1
            nxt[t]     = *(const bf16x8*)(W1 + ((f3 + t) * 2 + 1) * 512 + l8);
            nxt[3 + t] = *(const bf16x8*)(S1 + ((f3 + t) * 2 + 1) * 512 + l8);
        }
        compute_dual(Xs, 72, 0, cw, cs);
        #pragma unroll
        for (int t = 0; t < 3; ++t) { cw[t] = nxt[t]; cs[t] = nxt[3 + t]; }
        #pragma unroll
        for (int t = 0; t < 3; ++t) {                  // prefetch L2 ks0
            nxt[t]     = *(const bf16x8*)(W2 + ((f3 + t) * 6 + 0) * 512 + l8);
            nxt[3 + t] = *(const bf16x8*)(S2 + ((f3 + t) * 6 + 0) * 512 + l8);
        }
        compute_dual(Xs, 72, 1, cw, cs);
    }
    // epilogue L1 -> Hs (separate array from Xs: no race)
    #pragma unroll
    for (int t = 0; t < 3; ++t) {
        int colb = c0 + t * 16 + quad * 4;
        f32x4 bb = *(const f32x4*)(b1 + aH + colb);
        f32x4 sb = *(const f32x4*)(s1b + aH + colb);
        #pragma unroll
        for (int mt = 0; mt < 4; ++mt) {
            bf16x4 o;
            #pragma unroll
            for (int rg = 0; rg < 4; ++rg)
                o[rg] = (__bf16)(gelu_f(accT[mt * 3 + t][rg] + bb[rg]) + accS[mt * 3 + t][rg] + sb[rg]);
            *(bf16x4*)(Hs + (mt * 16 + ln) * 200 + colb) = o;
        }
    }
    #pragma unroll
    for (int i = 0; i < 12; ++i) { accT[i] = zero; accS[i] = zero; }
    __syncthreads();                                   // B2: h1 ready

    // ================= layer2 + skip2 (K=192, 6 chunks) =================
    #pragma unroll
    for (int ks = 0; ks < 6; ++ks) {
        bf16x8 cw[3], cs[3];
        #pragma unroll
        for (int t = 0; t < 3; ++t) { cw[t] = nxt[t]; cs[t] = nxt[3 + t]; }
        if (ks < 5) {
            #pragma unroll
            for (int t = 0; t < 3; ++t) {
                nxt[t]     = *(const bf16x8*)(W2 + ((f3 + t) * 6 + ks + 1) * 512 + l8);
                nxt[3 + t] = *(const bf16x8*)(S2 + ((f3 + t) * 6 + ks + 1) * 512 + l8);
            }
        } else {
            #pragma unroll
            for (int t = 0; t < 3; ++t)                // prefetch L3 ks0
                nxt[t] = *(const bf16x8*)(W3 + ((f3 + t) * 6 + 0) * 512 + l8);
        }
        compute_dual(Hs, 200, ks, cw, cs);
    }
    // h2 in fp32 registers (precision-critical residual)
    #pragma unroll
    for (int t = 0; t < 3; ++t) {
        int colb = c0 + t * 16 + quad * 4;
        f32x4 bb = *(const f32x4*)(b2 + aH + colb);
        f32x4 sb = *(const f32x4*)(s2b + aH + colb);
        #pragma unroll
        for (int mt = 0; mt < 4; ++mt)
            #pragma unroll
            for (int rg = 0; rg < 4; ++rg)
                h2f[mt * 3 + t][rg] = gelu_f(accT[mt * 3 + t][rg] + bb[rg]) + accS[mt * 3 + t][rg] + sb[rg];
    }
    #pragma unroll
    for (int i = 0; i < 12; ++i) accT[i] = zero;
    __syncthreads();                                   // B3: all h1 reads done
    #pragma unroll
    for (int t = 0; t < 3; ++t) {
        int colb = c0 + t * 16 + quad * 4;
        #pragma unroll
        for (int mt = 0; mt < 4; ++mt) {
            bf16x4 o;
            #pragma unroll
            for (int rg = 0; rg < 4; ++rg) o[rg] = (__bf16)h2f[mt * 3 + t][rg];
            *(bf16x4*)(Hs + (mt * 16 + ln) * 200 + colb) = o;
        }
    }
    __syncthreads();                                   // B4: h2 ready

    // ================= layer3 (K=192) =================
    bf16x8 ow6[6];
    #pragma unroll
    for (int ks = 0; ks < 6; ++ks) {
        bf16x8 cw[3];
        #pragma unroll
        for (int t = 0; t < 3; ++t) cw[t] = nxt[t];
        if (ks < 5) {
            #pragma unroll
            for (int t = 0; t < 3; ++t)
                nxt[t] = *(const bf16x8*)(W3 + ((f3 + t) * 6 + ks + 1) * 512 + l8);
        } else {
            #pragma unroll
            for (int kk = 0; kk < 6; ++kk)             // prefetch OW (shared by all waves)
                ow6[kk] = *(const bf16x8*)(OWp + kk * 512 + l8);
        }
        compute_single(ks, cw);
    }
    // h3 = (acc + b3 + h2)*hnw + hnb
    #pragma unroll
    for (int t = 0; t < 3; ++t) {
        int colb = c0 + t * 16 + quad * 4;
        f32x4 b3v = *(const f32x4*)(b3  + aH + colb);
        f32x4 nwv = *(const f32x4*)(hnw + aH + colb);
        f32x4 nbv = *(const f32x4*)(hnb + aH + colb);
        #pragma unroll
        for (int mt = 0; mt < 4; ++mt)
            #pragma unroll
            for (int rg = 0; rg < 4; ++rg)
                h2f[mt * 3 + t][rg] = fmaf(accT[mt * 3 + t][rg] + b3v[rg] + h2f[mt * 3 + t][rg],
                                           nwv[rg], nbv[rg]);
    }
    __syncthreads();                                   // B5: all h2 reads done
    #pragma unroll
    for (int t = 0; t < 3; ++t) {
        int colb = c0 + t * 16 + quad * 4;
        #pragma unroll
        for (int mt = 0; mt < 4; ++mt) {
            bf16x4 o;
            #pragma unroll
            for (int rg = 0; rg < 4; ++rg) o[rg] = (__bf16)h2f[mt * 3 + t][rg];
            *(bf16x4*)(Hs + (mt * 16 + ln) * 200 + colb) = o;
        }
    }
    __syncthreads();                                   // B6: h3 ready

    // ================= output (wave wv = row-tile wv) =================
    {
        f32x4 acco = zero;
        #pragma unroll
        for (int ks = 0; ks < 6; ++ks) {
            bf16x8 av = *(const bf16x8*)(Hs + (wv * 16 + ln) * 200 + ks * 32 + quad * 8);
            acco = MFMA(ow6[ks], av, acco);
        }
        if (quad == 0) {                               // o = rg (0..3), rows = wv*16+ln
            float* po = out + ((size_t)a * B_N + row0 + wv * 16 + ln) * O_N;
            po[0] = acco[0] + ob[a * O_N + 0];
            po[1] = acco[1] + ob[a * O_N + 1];
            po[2] = acco[2] + ob[a * O_N + 2];
        }
    }
}

extern "C" void kernel_launch(void* const* d_in, const int* in_sizes, int n_in,
                              void* d_out, int out_size, void* d_ws, size_t ws_size,
                              hipStream_t stream) {
    const float* x   = (const float*)d_in[0];
    const float* inw = (const float*)d_in[1];
    const float* inb = (const float*)d_in[2];
    const float* w1  = (const float*)d_in[3];
    const float* b1  = (const float*)d_in[4];
    const float* w2  = (const float*)d_in[5];
    const float* b2  = (const float*)d_in[6];
    const float* w3  = (const float*)d_in[7];
    const float* b3  = (const float*)d_in[8];
    const float* ow  = (const float*)d_in[9];
    const float* ob  = (const float*)d_in[10];
    const float* s1w = (const float*)d_in[11];
    const float* s1b = (const float*)d_in[12];
    const float* s2w = (const float*)d_in[13];
    const float* s2b = (const float*)d_in[14];
    const float* hnw = (const float*)d_in[15];
    const float* hnb = (const float*)d_in[16];

    __bf16* ws = (__bf16*)d_ws;   // 17.7 MB of d_ws

    prep_kernel<<<dim3(524), dim3(256), 0, stream>>>(w1, s1w, w2, s2w, w3, ow, ws);

    srek_mfma<<<dim3(A_N * (B_N / 64)), dim3(256), 0, stream>>>(
        x, inw, inb, b1, b2, b3, s1b, s2b, hnw, hnb, ob, ws, (float*)d_out);
}